// Round 2
// baseline (246.997 us; speedup 1.0000x reference)
//
#include <hip/hip_runtime.h>

#define G 128

// ---------------------------------------------------------------------------
// Kernel A: fused conv1 (3x3x3, 1->16, SAME) + relu + m0-mask + 2x2x2 maxpool.
// Sparsity-compacted: ~10% of centers are active (occ==0). Each block stages
// an 18^3 xm tile, builds a compacted list of active centers, processes list
// entries on consecutive lanes (dense 27x16 FMA per entry), and scatter-maxes
// into a pooled 8^3x16 LDS tile via atomicMax on float bits (valid: relu>=0).
// Block 512 flat; grid (8,8,16): conv region 16^3 per block.
// ---------------------------------------------------------------------------
__global__ __launch_bounds__(512)
void k_conv1_pool(const float* __restrict__ x, const int* __restrict__ occ,
                  const float* __restrict__ W1,
                  float* __restrict__ h1p, float* __restrict__ m1)
{
    __shared__ float          sx[18 * 18 * 18];
    __shared__ unsigned char  sm[18 * 18 * 18];
    __shared__ unsigned short lst[4096];
    __shared__ int            tile[8 * 8 * 8 * 16];   // pooled relu-max, float bits
    __shared__ int            cnt;

    const int bx = blockIdx.x, by = blockIdx.y;
    const int b  = blockIdx.z >> 3, bz = blockIdx.z & 7;
    const int tid = threadIdx.x;

    if (tid == 0) cnt = 0;

    const int z0 = bz * 16 - 1, y0 = by * 16 - 1, x0 = bx * 16 - 1;
    const int base_b = b * G * G * G;

    for (int i = tid; i < 18 * 18 * 18; i += 512) {
        int lz = i / 324, r = i % 324, ly = r / 18, lx = r % 18;
        int gz = z0 + lz, gy = y0 + ly, gx = x0 + lx;
        float v = 0.f; unsigned char mm = 0;
        if ((unsigned)gz < (unsigned)G && (unsigned)gy < (unsigned)G &&
            (unsigned)gx < (unsigned)G) {
            int gi = base_b + (gz * G + gy) * G + gx;
            mm = (occ[gi] == 0) ? 1 : 0;
            v  = mm ? x[gi] : 0.f;
        }
        sx[i] = v; sm[i] = mm;
    }
    for (int i = tid; i < 8192; i += 512) tile[i] = 0;
    __syncthreads();

    // list build: thread owns parent (tz,ty,tx); checks its 8 children
    const int tx = tid & 7, ty = (tid >> 3) & 7, tz = tid >> 6;
    int anym = 0;
    #pragma unroll
    for (int pos = 0; pos < 8; ++pos) {
        int dz = pos >> 2, dy = (pos >> 1) & 1, dx = pos & 1;
        int cz = 2 * tz + dz, cy = 2 * ty + dy, cx = 2 * tx + dx;  // conv-local
        if (sm[((cz + 1) * 18 + (cy + 1)) * 18 + (cx + 1)]) {
            anym = 1;
            int idx = atomicAdd(&cnt, 1);
            lst[idx] = (unsigned short)((cz << 8) | (cy << 4) | cx);
        }
    }
    __syncthreads();

    const int n = cnt;
    for (int i = tid; i < n; i += 512) {
        int e = lst[i];
        int cz = e >> 8, cy = (e >> 4) & 15, cx = e & 15;
        float acc[16];
        #pragma unroll
        for (int c = 0; c < 16; ++c) acc[c] = 0.f;
        for (int kz = 0; kz < 3; ++kz)
        for (int ky = 0; ky < 3; ++ky)
        #pragma unroll
        for (int kx = 0; kx < 3; ++kx) {
            float v = sx[((cz + kz) * 18 + (cy + ky)) * 18 + (cx + kx)];
            const float* w = &W1[((kz * 3 + ky) * 3 + kx) * 16];
            #pragma unroll
            for (int c = 0; c < 16; ++c) acc[c] += v * w[c];
        }
        int pbase = (((cz >> 1) * 8 + (cy >> 1)) * 8 + (cx >> 1)) * 16;
        #pragma unroll
        for (int c = 0; c < 16; ++c) {
            float r = acc[c] > 0.f ? acc[c] : 0.f;
            if (r > 0.f) atomicMax(&tile[pbase + c], __float_as_int(r));
        }
    }
    __syncthreads();

    // writeback: thread = parent tid (linear (tz*8+ty)*8+tx == tid)
    const int pz = bz * 8 + tz, py = by * 8 + ty, px = bx * 8 + tx;
    const int vidx = ((b * 64 + pz) * 64 + py) * 64 + px;
    const int tb = tid * 16;
    float4* o = (float4*)&h1p[vidx * 16];
    o[0] = make_float4(__int_as_float(tile[tb + 0]),  __int_as_float(tile[tb + 1]),
                       __int_as_float(tile[tb + 2]),  __int_as_float(tile[tb + 3]));
    o[1] = make_float4(__int_as_float(tile[tb + 4]),  __int_as_float(tile[tb + 5]),
                       __int_as_float(tile[tb + 6]),  __int_as_float(tile[tb + 7]));
    o[2] = make_float4(__int_as_float(tile[tb + 8]),  __int_as_float(tile[tb + 9]),
                       __int_as_float(tile[tb + 10]), __int_as_float(tile[tb + 11]));
    o[3] = make_float4(__int_as_float(tile[tb + 12]), __int_as_float(tile[tb + 13]),
                       __int_as_float(tile[tb + 14]), __int_as_float(tile[tb + 15]));
    m1[vidx] = anym ? 1.f : 0.f;
}

// ---------------------------------------------------------------------------
// Kernel B: fused conv2 (3x3x3, 16->4, SAME at 64^3) + relu + m1-mask + pool.
// One thread per conv voxel (8^3 per block, 512 thr); 10^3 halo tile staged
// in LDS channel-major [ci][z][y][x pad 12] (<=2-way bank conflicts).
// Pool 2x2x2 via __shfl_xor (pool group = lane bits 0..2). Emits h2 + m2.
// Grid (8,8,16).
// ---------------------------------------------------------------------------
__global__ __launch_bounds__(512)
void k_conv2_pool(const float* __restrict__ h1p, const float* __restrict__ m1,
                  const float* __restrict__ W2,
                  float* __restrict__ h2, float* __restrict__ m2)
{
    __shared__ float tile[16 * 10 * 10 * 12];   // 76.8 KB

    const int bx = blockIdx.x, by = blockIdx.y;
    const int b  = blockIdx.z >> 3, bz = blockIdx.z & 7;
    const int tid = threadIdx.x;

    const int z0 = bz * 8 - 1, y0 = by * 8 - 1, x0 = bx * 8 - 1;

    for (int i = tid; i < 1000; i += 512) {
        int tz = i / 100, r = i % 100, ty = r / 10, txl = r % 10;
        int gz = z0 + tz, gy = y0 + ty, gx = x0 + txl;
        float c[16];
        #pragma unroll
        for (int ci = 0; ci < 16; ++ci) c[ci] = 0.f;
        if ((unsigned)gz < 64u && (unsigned)gy < 64u && (unsigned)gx < 64u) {
            const float4* p4 = (const float4*)&h1p[(((b * 64 + gz) * 64 + gy) * 64 + gx) * 16];
            float4 f0 = p4[0], f1 = p4[1], f2 = p4[2], f3 = p4[3];
            c[0]=f0.x; c[1]=f0.y; c[2]=f0.z; c[3]=f0.w;
            c[4]=f1.x; c[5]=f1.y; c[6]=f1.z; c[7]=f1.w;
            c[8]=f2.x; c[9]=f2.y; c[10]=f2.z; c[11]=f2.w;
            c[12]=f3.x; c[13]=f3.y; c[14]=f3.z; c[15]=f3.w;
        }
        int base = tz * 120 + ty * 12 + txl;
        #pragma unroll
        for (int ci = 0; ci < 16; ++ci) tile[ci * 1200 + base] = c[ci];
    }
    __syncthreads();

    // thread -> conv voxel; pool group in lane bits 0..2
    const int dx = tid & 1, dy = (tid >> 1) & 1, dz = (tid >> 2) & 1;
    const int X1 = (tid >> 3) & 3, Y1 = (tid >> 5) & 3, Z1 = (tid >> 7) & 3;
    const int cx = (X1 << 1) | dx, cy = (Y1 << 1) | dy, cz = (Z1 << 1) | dz;

    float a0 = 0.f, a1 = 0.f, a2 = 0.f, a3 = 0.f;
    for (int kz = 0; kz < 3; ++kz)
    for (int ky = 0; ky < 3; ++ky)
    #pragma unroll
    for (int kx = 0; kx < 3; ++kx) {
        int tbase = (cz + kz) * 120 + (cy + ky) * 12 + (cx + kx);
        const float* w = &W2[((kz * 3 + ky) * 3 + kx) * 64];
        #pragma unroll
        for (int ci = 0; ci < 16; ++ci) {
            float v = tile[ci * 1200 + tbase];
            a0 += v * w[ci * 4 + 0];
            a1 += v * w[ci * 4 + 1];
            a2 += v * w[ci * 4 + 2];
            a3 += v * w[ci * 4 + 3];
        }
    }

    const int gcz = bz * 8 + cz, gcy = by * 8 + cy, gcx = bx * 8 + cx;
    float mv = m1[((b * 64 + gcz) * 64 + gcy) * 64 + gcx];
    float r0 = fmaxf(a0, 0.f) * mv;
    float r1 = fmaxf(a1, 0.f) * mv;
    float r2 = fmaxf(a2, 0.f) * mv;
    float r3 = fmaxf(a3, 0.f) * mv;

    #pragma unroll
    for (int mask = 1; mask <= 4; mask <<= 1) {
        r0 = fmaxf(r0, __shfl_xor(r0, mask));
        r1 = fmaxf(r1, __shfl_xor(r1, mask));
        r2 = fmaxf(r2, __shfl_xor(r2, mask));
        r3 = fmaxf(r3, __shfl_xor(r3, mask));
        mv = fmaxf(mv, __shfl_xor(mv, mask));
    }
    if ((tid & 7) == 0) {
        int pz = bz * 4 + Z1, py = by * 4 + Y1, px = bx * 4 + X1;
        int oidx = ((b * 32 + pz) * 32 + py) * 32 + px;
        *(float4*)&h2[oidx * 4] = make_float4(r0, r1, r2, r3);
        m2[oidx] = mv;
    }
}

// ---------------------------------------------------------------------------
// Kernel C: fused decoder. tconv1(2^3 s2, 4->16)+relu then tconv2+sigmoid,
// masked by m2 (m3/m4 of all 64 children == m2[parent]). JAX conv_transpose
// flips the kernel: out[2i+a] = x[i]*W[1-a]. One thread per (parent, a, bb):
// 262144 threads, 4 coalesced float4 stores each.
// ---------------------------------------------------------------------------
__global__ __launch_bounds__(256)
void k_decoder(const float* __restrict__ h2, const float* __restrict__ m2,
               const float* __restrict__ Wt1, const float* __restrict__ Wt2,
               float* __restrict__ out)
{
    const int T  = blockIdx.x * 256 + threadIdx.x;   // 0..262143
    const int px = T & 31;
    const int a  = (T >> 5) & 1;
    const int bb = (T >> 6) & 1;
    const int py = (T >> 7) & 31;
    const int pz = (T >> 12) & 31;
    const int b  = T >> 17;
    const int pidx = ((b * 32 + pz) * 32 + py) * 32 + px;

    const float m = m2[pidx];
    const float4 hv = *(const float4*)&h2[pidx * 4];

    // th1 at 64^3 voxels (2pz+a, 2py+bb, 2px+c), c=0,1; weights Wt1[1-a][1-bb][1-c]
    float t0[16], t1[16];
    const int base0 = (((1 - a) * 2 + (1 - bb)) * 2 + 1) * 64;  // c=0 -> kc=1
    const int base1 = (((1 - a) * 2 + (1 - bb)) * 2 + 0) * 64;  // c=1 -> kc=0
    #pragma unroll
    for (int ch = 0; ch < 16; ++ch) {
        float s0 = hv.x * Wt1[base0 + ch]      + hv.y * Wt1[base0 + 16 + ch]
                 + hv.z * Wt1[base0 + 32 + ch] + hv.w * Wt1[base0 + 48 + ch];
        float s1 = hv.x * Wt1[base1 + ch]      + hv.y * Wt1[base1 + 16 + ch]
                 + hv.z * Wt1[base1 + 32 + ch] + hv.w * Wt1[base1 + 48 + ch];
        t0[ch] = s0 > 0.f ? s0 : 0.f;
        t1[ch] = s1 > 0.f ? s1 : 0.f;
    }
    #pragma unroll
    for (int e = 0; e < 2; ++e) {
        #pragma unroll
        for (int f = 0; f < 2; ++f) {
            const int d = 4 * pz + 2 * a + e;
            const int h = 4 * py + 2 * bb + f;
            const int base_ef = ((1 - e) * 2 + (1 - f)) * 2;
            const float* wg0 = Wt2 + (base_ef + 1) * 16;  // g=0 -> kg=1
            const float* wg1 = Wt2 + (base_ef + 0) * 16;  // g=1 -> kg=0
            float s00 = 0.f, s01 = 0.f, s10 = 0.f, s11 = 0.f;
            #pragma unroll
            for (int ch = 0; ch < 16; ++ch) {
                s00 += t0[ch] * wg0[ch];
                s01 += t0[ch] * wg1[ch];
                s10 += t1[ch] * wg0[ch];
                s11 += t1[ch] * wg1[ch];
            }
            float4 o;
            o.x = m / (1.f + __expf(-s00));
            o.y = m / (1.f + __expf(-s01));
            o.z = m / (1.f + __expf(-s10));
            o.w = m / (1.f + __expf(-s11));
            *(float4*)&out[((b * G + d) * G + h) * G + 4 * px] = o;
        }
    }
}

extern "C" void kernel_launch(void* const* d_in, const int* in_sizes, int n_in,
                              void* d_out, int out_size, void* d_ws, size_t ws_size,
                              hipStream_t stream) {
    (void)in_sizes; (void)n_in; (void)out_size; (void)ws_size;
    const float* x   = (const float*)d_in[0];
    const float* W1  = (const float*)d_in[1];
    const float* W2  = (const float*)d_in[2];
    const float* Wt1 = (const float*)d_in[3];
    const float* Wt2 = (const float*)d_in[4];
    const int*   occ = (const int*)d_in[5];
    float* out = (float*)d_out;

    float* ws  = (float*)d_ws;
    float* h1p = ws;                          // 2*64^3*16 floats
    float* m1  = h1p + 2 * 64 * 64 * 64 * 16; // 2*64^3
    float* h2  = m1  + 2 * 64 * 64 * 64;      // 2*32^3*4
    float* m2v = h2  + 2 * 32 * 32 * 32 * 4;  // 2*32^3

    k_conv1_pool<<<dim3(8, 8, 16), dim3(512), 0, stream>>>(x, occ, W1, h1p, m1);
    k_conv2_pool<<<dim3(8, 8, 16), dim3(512), 0, stream>>>(h1p, m1, W2, h2, m2v);
    k_decoder<<<dim3(1024), dim3(256), 0, stream>>>(h2, m2v, Wt1, Wt2, out);
}

// Round 3
// 239.465 us; speedup vs baseline: 1.0315x; 1.0315x over previous
//
#include <hip/hip_runtime.h>

#define G 128

// ---------------------------------------------------------------------------
// Kernel A: fused conv1 (3x3x3, 1->16, SAME) + relu + m0-mask + 2x2x2 maxpool.
// Sparsity compaction, contention-free:
//  - list build: ballot + ONE atomicAdd per wave per pos (not per element)
//  - pooled scatter: atomicMax into tile with row stride 17 (17p mod 32 spans
//    all banks; within a pos-plane each parent has <=1 child -> no same-addr
//    contention within a wave)
// Block 512 flat; grid (8,8,16): conv region 16^3, parents 8^3 (1/thread).
// LDS: sx 23.3K + sm 5.8K + lst 8K + tile 34.8K = ~72KB -> 2 blocks/CU.
// ---------------------------------------------------------------------------
__global__ __launch_bounds__(512)
void k_conv1_pool(const float* __restrict__ x, const int* __restrict__ occ,
                  const float* __restrict__ W1,
                  float* __restrict__ h1p, float* __restrict__ m1)
{
    __shared__ float          sx[18 * 18 * 18];
    __shared__ unsigned char  sm[18 * 18 * 18];
    __shared__ unsigned short lst[4096];
    __shared__ int            tile[512 * 17];   // [parent][17], float bits
    __shared__ int            cnt;

    const int bx = blockIdx.x, by = blockIdx.y;
    const int b  = blockIdx.z >> 3, bz = blockIdx.z & 7;
    const int tid = threadIdx.x;

    if (tid == 0) cnt = 0;

    const int z0 = bz * 16 - 1, y0 = by * 16 - 1, x0 = bx * 16 - 1;
    const int base_b = b * G * G * G;

    for (int i = tid; i < 18 * 18 * 18; i += 512) {
        int lz = i / 324, r = i % 324, ly = r / 18, lx = r % 18;
        int gz = z0 + lz, gy = y0 + ly, gx = x0 + lx;
        float v = 0.f; unsigned char mm = 0;
        if ((unsigned)gz < (unsigned)G && (unsigned)gy < (unsigned)G &&
            (unsigned)gx < (unsigned)G) {
            int gi = base_b + (gz * G + gy) * G + gx;
            mm = (occ[gi] == 0) ? 1 : 0;
            v  = mm ? x[gi] : 0.f;
        }
        sx[i] = v; sm[i] = mm;
    }
    for (int i = tid; i < 512 * 17; i += 512) tile[i] = 0;
    __syncthreads();

    // ---- list build: thread = parent (tz,ty,tx); pos-major ordering ----
    const int tx = tid & 7, ty = (tid >> 3) & 7, tz = tid >> 6;
    const int lane = tid & 63;
    int anym = 0;
    #pragma unroll
    for (int pos = 0; pos < 8; ++pos) {
        int dz = pos >> 2, dy = (pos >> 1) & 1, dx = pos & 1;
        int cz = 2 * tz + dz, cy = 2 * ty + dy, cx = 2 * tx + dx;  // conv-local
        int flag = sm[((cz + 1) * 18 + (cy + 1)) * 18 + (cx + 1)];
        anym |= flag;
        unsigned long long mb = __ballot(flag);
        int wbase;
        if (lane == 0) wbase = atomicAdd(&cnt, __popcll(mb));
        wbase = __shfl(wbase, 0);
        if (flag) {
            int lofs = __popcll(mb & ((1ull << lane) - 1ull));
            lst[wbase + lofs] = (unsigned short)((cz << 8) | (cy << 4) | cx);
        }
    }
    __syncthreads();

    // ---- dense compute on compacted list (full lane utilization) ----
    const int n = cnt;
    for (int i = tid; i < n; i += 512) {
        int e = lst[i];
        int cz = e >> 8, cy = (e >> 4) & 15, cx = e & 15;
        float acc[16];
        #pragma unroll
        for (int c = 0; c < 16; ++c) acc[c] = 0.f;
        for (int kz = 0; kz < 3; ++kz)
        for (int ky = 0; ky < 3; ++ky)
        #pragma unroll
        for (int kx = 0; kx < 3; ++kx) {
            float v = sx[((cz + kz) * 18 + (cy + ky)) * 18 + (cx + kx)];
            const float* w = &W1[((kz * 3 + ky) * 3 + kx) * 16];
            #pragma unroll
            for (int c = 0; c < 16; ++c) acc[c] += v * w[c];
        }
        int pb = (((cz >> 1) * 8 + (cy >> 1)) * 8 + (cx >> 1)) * 17;
        #pragma unroll
        for (int c = 0; c < 16; ++c) {
            float r = acc[c] > 0.f ? acc[c] : 0.f;
            if (r > 0.f) atomicMax(&tile[pb + c], __float_as_int(r));
        }
    }
    __syncthreads();

    // ---- writeback: thread = parent; tile stride-17 reads are 2-way max ----
    const int pz = bz * 8 + tz, py = by * 8 + ty, px = bx * 8 + tx;
    const int vidx = ((b * 64 + pz) * 64 + py) * 64 + px;
    const int tb = tid * 17;
    float4* o = (float4*)&h1p[vidx * 16];
    o[0] = make_float4(__int_as_float(tile[tb + 0]),  __int_as_float(tile[tb + 1]),
                       __int_as_float(tile[tb + 2]),  __int_as_float(tile[tb + 3]));
    o[1] = make_float4(__int_as_float(tile[tb + 4]),  __int_as_float(tile[tb + 5]),
                       __int_as_float(tile[tb + 6]),  __int_as_float(tile[tb + 7]));
    o[2] = make_float4(__int_as_float(tile[tb + 8]),  __int_as_float(tile[tb + 9]),
                       __int_as_float(tile[tb + 10]), __int_as_float(tile[tb + 11]));
    o[3] = make_float4(__int_as_float(tile[tb + 12]), __int_as_float(tile[tb + 13]),
                       __int_as_float(tile[tb + 14]), __int_as_float(tile[tb + 15]));
    m1[vidx] = anym ? 1.f : 0.f;
}

// ---------------------------------------------------------------------------
// Kernel B: fused conv2 (3x3x3, 16->4, SAME at 64^3) + relu + m1-mask + pool.
// 256 threads/block, conv region 8^3; each thread computes 2 x-adjacent conv
// voxels (= one pool x-pair, tap value reuse 36 instead of 54 positions).
// Channels split into two passes of 8 (tile = 2 float4-groups, 41.6KB ->
// 3 blocks/CU). Tile layout idx(g,z,y,x) = g*1300 + z*130 + y*13 + x in
// float4 units: y-stride 52 words (== 20 mod 32), z-stride 520 (== 8) ->
// b128 reads spread across all 32 banks. Pool via 2x shfl_xor + in-reg x-max.
// Grid (8,8,16).
// ---------------------------------------------------------------------------
__global__ __launch_bounds__(256)
void k_conv2_pool(const float* __restrict__ h1p, const float* __restrict__ m1,
                  const float* __restrict__ W2,
                  float* __restrict__ h2, float* __restrict__ m2)
{
    __shared__ float4 tile[2 * 1300];   // 41.6 KB

    const int bx = blockIdx.x, by = blockIdx.y;
    const int b  = blockIdx.z >> 3, bz = blockIdx.z & 7;
    const int tid = threadIdx.x;

    const int dy = tid & 1, dz = (tid >> 1) & 1;
    const int qx = (tid >> 2) & 3, Y = (tid >> 4) & 3, Z = (tid >> 6) & 3;
    const int cx0 = 2 * qx, cy = 2 * Y + dy, cz = 2 * Z + dz;

    const int z0 = bz * 8 - 1, y0 = by * 8 - 1, x0 = bx * 8 - 1;

    float acc0[4] = {0.f, 0.f, 0.f, 0.f};   // voxel cx0
    float acc1[4] = {0.f, 0.f, 0.f, 0.f};   // voxel cx0+1

    for (int h = 0; h < 2; ++h) {
        if (h) __syncthreads();             // protect tile reuse
        for (int v = tid; v < 1000; v += 256) {
            int z = v / 100, r = v % 100, y = r / 10, xx = r % 10;
            int gz = z0 + z, gy = y0 + y, gx = x0 + xx;
            float4 a = make_float4(0.f, 0.f, 0.f, 0.f);
            float4 c = a;
            if ((unsigned)gz < 64u && (unsigned)gy < 64u && (unsigned)gx < 64u) {
                const float4* p4 = (const float4*)&h1p[(((b * 64 + gz) * 64 + gy) * 64 + gx) * 16];
                a = p4[2 * h];
                c = p4[2 * h + 1];
            }
            int t = z * 130 + y * 13 + xx;
            tile[t]        = a;
            tile[1300 + t] = c;
        }
        __syncthreads();

        for (int kz = 0; kz < 3; ++kz)
        for (int ky = 0; ky < 3; ++ky) {
            const int rb = (cz + kz) * 130 + (cy + ky) * 13 + cx0;
            const float* wrow = &W2[((kz * 3 + ky) * 3) * 64 + h * 32];
            #pragma unroll
            for (int xi = 0; xi < 4; ++xi) {
                float4 v0 = tile[rb + xi];
                float4 v1 = tile[1300 + rb + xi];
                #pragma unroll
                for (int j = 0; j < 2; ++j) {
                    int kx = xi - j;
                    if (kx < 0 || kx > 2) continue;
                    const float* w = wrow + kx * 64;   // 32 floats: g0 then g1
                    float* acc = j ? acc1 : acc0;
                    #pragma unroll
                    for (int co = 0; co < 4; ++co) {
                        acc[co] += v0.x * w[0  + co] + v0.y * w[4  + co]
                                 + v0.z * w[8  + co] + v0.w * w[12 + co]
                                 + v1.x * w[16 + co] + v1.y * w[20 + co]
                                 + v1.z * w[24 + co] + v1.w * w[28 + co];
                    }
                }
            }
        }
    }

    // mask + relu + 2x2x2 pool (x in-register, y/z via shfl)
    const int gcz = bz * 8 + cz, gcy = by * 8 + cy, gcx = bx * 8 + cx0;
    const float mv0 = m1[((b * 64 + gcz) * 64 + gcy) * 64 + gcx];
    const float mv1 = m1[((b * 64 + gcz) * 64 + gcy) * 64 + gcx + 1];
    float m = fmaxf(mv0, mv1);
    float r[4];
    #pragma unroll
    for (int co = 0; co < 4; ++co)
        r[co] = fmaxf(fmaxf(acc0[co], 0.f) * mv0, fmaxf(acc1[co], 0.f) * mv1);

    #pragma unroll
    for (int mask = 1; mask <= 2; mask <<= 1) {
        #pragma unroll
        for (int co = 0; co < 4; ++co) r[co] = fmaxf(r[co], __shfl_xor(r[co], mask));
        m = fmaxf(m, __shfl_xor(m, mask));
    }
    if ((tid & 3) == 0) {
        int pz = bz * 4 + Z, py = by * 4 + Y, px = bx * 4 + qx;
        int oidx = ((b * 32 + pz) * 32 + py) * 32 + px;
        *(float4*)&h2[oidx * 4] = make_float4(r[0], r[1], r[2], r[3]);
        m2[oidx] = m;
    }
}

// ---------------------------------------------------------------------------
// Kernel C: fused decoder. tconv1(2^3 s2, 4->16)+relu then tconv2+sigmoid,
// masked by m2 (m3/m4 of all 64 children == m2[parent]). JAX conv_transpose
// flips the kernel: out[2i+a] = x[i]*W[1-a]. One thread per (parent, a, bb).
// ---------------------------------------------------------------------------
__global__ __launch_bounds__(256)
void k_decoder(const float* __restrict__ h2, const float* __restrict__ m2,
               const float* __restrict__ Wt1, const float* __restrict__ Wt2,
               float* __restrict__ out)
{
    const int T  = blockIdx.x * 256 + threadIdx.x;   // 0..262143
    const int px = T & 31;
    const int a  = (T >> 5) & 1;
    const int bb = (T >> 6) & 1;
    const int py = (T >> 7) & 31;
    const int pz = (T >> 12) & 31;
    const int b  = T >> 17;
    const int pidx = ((b * 32 + pz) * 32 + py) * 32 + px;

    const float m = m2[pidx];
    const float4 hv = *(const float4*)&h2[pidx * 4];

    float t0[16], t1[16];
    const int base0 = (((1 - a) * 2 + (1 - bb)) * 2 + 1) * 64;  // c=0 -> kc=1
    const int base1 = (((1 - a) * 2 + (1 - bb)) * 2 + 0) * 64;  // c=1 -> kc=0
    #pragma unroll
    for (int ch = 0; ch < 16; ++ch) {
        float s0 = hv.x * Wt1[base0 + ch]      + hv.y * Wt1[base0 + 16 + ch]
                 + hv.z * Wt1[base0 + 32 + ch] + hv.w * Wt1[base0 + 48 + ch];
        float s1 = hv.x * Wt1[base1 + ch]      + hv.y * Wt1[base1 + 16 + ch]
                 + hv.z * Wt1[base1 + 32 + ch] + hv.w * Wt1[base1 + 48 + ch];
        t0[ch] = s0 > 0.f ? s0 : 0.f;
        t1[ch] = s1 > 0.f ? s1 : 0.f;
    }
    #pragma unroll
    for (int e = 0; e < 2; ++e) {
        #pragma unroll
        for (int f = 0; f < 2; ++f) {
            const int d = 4 * pz + 2 * a + e;
            const int h = 4 * py + 2 * bb + f;
            const int base_ef = ((1 - e) * 2 + (1 - f)) * 2;
            const float* wg0 = Wt2 + (base_ef + 1) * 16;  // g=0 -> kg=1
            const float* wg1 = Wt2 + (base_ef + 0) * 16;  // g=1 -> kg=0
            float s00 = 0.f, s01 = 0.f, s10 = 0.f, s11 = 0.f;
            #pragma unroll
            for (int ch = 0; ch < 16; ++ch) {
                s00 += t0[ch] * wg0[ch];
                s01 += t0[ch] * wg1[ch];
                s10 += t1[ch] * wg0[ch];
                s11 += t1[ch] * wg1[ch];
            }
            float4 o;
            o.x = m / (1.f + __expf(-s00));
            o.y = m / (1.f + __expf(-s01));
            o.z = m / (1.f + __expf(-s10));
            o.w = m / (1.f + __expf(-s11));
            *(float4*)&out[((b * G + d) * G + h) * G + 4 * px] = o;
        }
    }
}

extern "C" void kernel_launch(void* const* d_in, const int* in_sizes, int n_in,
                              void* d_out, int out_size, void* d_ws, size_t ws_size,
                              hipStream_t stream) {
    (void)in_sizes; (void)n_in; (void)out_size; (void)ws_size;
    const float* x   = (const float*)d_in[0];
    const float* W1  = (const float*)d_in[1];
    const float* W2  = (const float*)d_in[2];
    const float* Wt1 = (const float*)d_in[3];
    const float* Wt2 = (const float*)d_in[4];
    const int*   occ = (const int*)d_in[5];
    float* out = (float*)d_out;

    float* ws  = (float*)d_ws;
    float* h1p = ws;                          // 2*64^3*16 floats
    float* m1  = h1p + 2 * 64 * 64 * 64 * 16; // 2*64^3
    float* h2  = m1  + 2 * 64 * 64 * 64;      // 2*32^3*4
    float* m2v = h2  + 2 * 32 * 32 * 32 * 4;  // 2*32^3

    k_conv1_pool<<<dim3(8, 8, 16), dim3(512), 0, stream>>>(x, occ, W1, h1p, m1);
    k_conv2_pool<<<dim3(8, 8, 16), dim3(256), 0, stream>>>(h1p, m1, W2, h2, m2v);
    k_decoder<<<dim3(1024), dim3(256), 0, stream>>>(h2, m2v, Wt1, Wt2, out);
}